// Round 1
// baseline (74.630 us; speedup 1.0000x reference)
//
#include <hip/hip_runtime.h>
#include <hip/hip_bf16.h>

// Problem constants (fixed by setup_inputs)
#define NG   256   // graphs
#define NPG  64    // nodes per graph
#define INF  128   // in features (K)
#define OUTF 128   // out features (N)
#define NH   16    // heads

#define LDSK 136   // padded LDS k-stride (bf16 units); rows stay 16B-aligned

typedef __attribute__((ext_vector_type(8))) short bf16x8;           // 8 bf16 = 4 VGPRs
typedef __attribute__((ext_vector_type(8))) unsigned short u16x8;   // 16B
typedef __attribute__((ext_vector_type(4))) float f32x4;            // MFMA accumulator

__device__ __forceinline__ unsigned short f2bf(float f) {
    union { float f; unsigned int i; } c; c.f = f;
    unsigned int r = c.i + 0x7fffu + ((c.i >> 16) & 1u);  // round-to-nearest-even
    return (unsigned short)(r >> 16);
}

// ---------------------------------------------------------------------------
// Kernel 1 (one-shot, ~1 MiB): W [NH][INF][OUTF] f32  ->  Wt [NH][OUTF][INF] bf16
// 128 blocks: block b handles head b>>3, output-row tile n0=(b&7)*16 (16 rows).
// Read coalesced float4 along n, transpose through a tiny LDS tile, store
// coalesced u16x8 along k.
// ---------------------------------------------------------------------------
__global__ __launch_bounds__(256) void wconv_kernel(
    const float* __restrict__ W, unsigned short* __restrict__ Wt)
{
    __shared__ unsigned short T[16 * LDSK];  // 4352 B
    int b  = (int)blockIdx.x;                // NH*8 = 128
    int h  = b >> 3;
    int n0 = (b & 7) * 16;
    int t  = (int)threadIdx.x;
    const float* Wh = W + h * (INF * OUTF);
#pragma unroll
    for (int i = 0; i < 2; ++i) {
        int flat = i * 256 + t;              // 512 float4 = 128 k-rows x 16 n
        int k = flat >> 2;
        int c = (flat & 3) * 4;
        float4 v = *(const float4*)(Wh + k * OUTF + n0 + c);
        T[(c + 0) * LDSK + k] = f2bf(v.x);
        T[(c + 1) * LDSK + k] = f2bf(v.y);
        T[(c + 2) * LDSK + k] = f2bf(v.z);
        T[(c + 3) * LDSK + k] = f2bf(v.w);
    }
    __syncthreads();
    int n  = t >> 4;                         // 16 rows
    int kc = t & 15;                         // 16 x u16x8 per row
    u16x8 r = *(const u16x8*)(&T[n * LDSK + kc * 8]);  // conflict-free (8/bank)
    *(u16x8*)(Wt + h * (OUTF * INF) + (n0 + n) * INF + kc * 8) = r;
}

// ---------------------------------------------------------------------------
// Kernel 2: barrier-free, LDS-free GEMM. One block per graph, 8 waves.
// Wave computes 16 rows x 64 cols. A from X (fp32->bf16 in regs); B as direct
// bf16x8 loads from L2-resident pre-transposed Wt (k-contiguous). All 24 global
// loads issued up front so HBM/L2 latency overlaps; no __syncthreads anywhere.
// ---------------------------------------------------------------------------
__global__ __launch_bounds__(512) void mhl_gemm_kernel(
    const float* __restrict__ X,               // [NG*NPG][INF] fp32
    const int*   __restrict__ head,            // [NG]
    const unsigned short* __restrict__ Wt,     // [NH][OUTF][INF] bf16
    const float* __restrict__ bias,            // [NH][OUTF] fp32
    float*       __restrict__ Y)               // [NG*NPG][OUTF] fp32
{
    int g = (int)blockIdx.x;
    int h = head[g];
    int t = (int)threadIdx.x;
    int wave = t >> 6, lane = t & 63;
    int quad = lane >> 4, l16 = lane & 15;
    int mrow = (wave & 3) * 16;    // row tile within graph
    int ncol = (wave >> 2) * 64;   // column half

    // Issue X loads first (HBM-cold each iteration).
    const float* Xg = X + (g * NPG + mrow + l16) * INF + quad * 8;
    float4 xv[8];
#pragma unroll
    for (int kt = 0; kt < 4; ++kt) {
        xv[2 * kt]     = *(const float4*)(Xg + kt * 32);
        xv[2 * kt + 1] = *(const float4*)(Xg + kt * 32 + 4);
    }

    // B fragments straight from global: Wt[h][n][k], k-contiguous bf16x8.
    // Layout identical to the harness-verified LDS read: b[j]=B[k=quad*8+j][n].
    const unsigned short* Wb = Wt + h * (OUTF * INF) + quad * 8;
    bf16x8 bfrag[4][4];
#pragma unroll
    for (int nt = 0; nt < 4; ++nt) {
        const unsigned short* Wn = Wb + (ncol + nt * 16 + l16) * INF;
#pragma unroll
        for (int kt = 0; kt < 4; ++kt)
            bfrag[nt][kt] = *(const bf16x8*)(Wn + kt * 32);
    }

    // Convert A while B loads are in flight.
    bf16x8 a[4];
#pragma unroll
    for (int kt = 0; kt < 4; ++kt) {
        float vv[8] __attribute__((aligned(16)));
        *(float4*)(&vv[0]) = xv[2 * kt];
        *(float4*)(&vv[4]) = xv[2 * kt + 1];
#pragma unroll
        for (int j = 0; j < 8; ++j) a[kt][j] = (short)f2bf(vv[j]);
    }

    f32x4 acc[4];
#pragma unroll
    for (int nt = 0; nt < 4; ++nt) acc[nt] = (f32x4){0.f, 0.f, 0.f, 0.f};
#pragma unroll
    for (int nt = 0; nt < 4; ++nt)
#pragma unroll
        for (int kt = 0; kt < 4; ++kt)
            acc[nt] = __builtin_amdgcn_mfma_f32_16x16x32_bf16(a[kt], bfrag[nt][kt], acc[nt], 0, 0, 0);

    // Epilogue: C/D layout col=lane&15, row=quad*4+reg (m89-verified).
    // Nontemporal: Y is write-once; keep Wt/bias resident in L2.
    float* Yg = Y + (g * NPG + mrow) * OUTF + ncol;
#pragma unroll
    for (int nt = 0; nt < 4; ++nt) {
        float bv = bias[h * OUTF + ncol + nt * 16 + l16];
#pragma unroll
        for (int r = 0; r < 4; ++r)
            __builtin_nontemporal_store(acc[nt][r] + bv,
                &Yg[(quad * 4 + r) * OUTF + nt * 16 + l16]);
    }
}

// ---------------------------------------------------------------------------
// Fallback (previous harness-verified fused kernel) — used only if ws_size
// is too small for the 512 KiB Wt scratch.
// ---------------------------------------------------------------------------
__global__ __launch_bounds__(512) void mhl_fused_kernel(
    const float* __restrict__ X, const int* __restrict__ head,
    const float* __restrict__ W, const float* __restrict__ bias,
    float* __restrict__ Y)
{
    __shared__ unsigned short Wl[OUTF * LDSK];
    int g = (int)blockIdx.x;
    int h = head[g];
    int t = (int)threadIdx.x;
    {
        int k  = t >> 2;
        int c0 = (t & 3) * 32;
        const float* src = W + h * (INF * OUTF) + k * OUTF + c0;
#pragma unroll
        for (int j = 0; j < 32; j += 4) {
            float4 v = *(const float4*)(src + j);
            Wl[(c0 + j + 0) * LDSK + k] = f2bf(v.x);
            Wl[(c0 + j + 1) * LDSK + k] = f2bf(v.y);
            Wl[(c0 + j + 2) * LDSK + k] = f2bf(v.z);
            Wl[(c0 + j + 3) * LDSK + k] = f2bf(v.w);
        }
    }
    __syncthreads();
    int wave = t >> 6, lane = t & 63;
    int quad = lane >> 4, l16 = lane & 15;
    int mrow = (wave & 3) * 16;
    int ncol = (wave >> 2) * 64;
    const float* Xg = X + (g * NPG + mrow + l16) * INF + quad * 8;
    bf16x8 a[4];
#pragma unroll
    for (int kt = 0; kt < 4; ++kt) {
        float v[8] __attribute__((aligned(16)));
        *(float4*)(&v[0]) = *(const float4*)(Xg + kt * 32);
        *(float4*)(&v[4]) = *(const float4*)(Xg + kt * 32 + 4);
#pragma unroll
        for (int j = 0; j < 8; ++j) a[kt][j] = (short)f2bf(v[j]);
    }
    f32x4 acc[4];
#pragma unroll
    for (int nt = 0; nt < 4; ++nt) acc[nt] = (f32x4){0.f, 0.f, 0.f, 0.f};
#pragma unroll
    for (int nt = 0; nt < 4; ++nt) {
        const unsigned short* Wn = &Wl[(ncol + nt * 16 + l16) * LDSK + quad * 8];
#pragma unroll
        for (int kt = 0; kt < 4; ++kt) {
            bf16x8 bv = *(const bf16x8*)(Wn + kt * 32);
            acc[nt] = __builtin_amdgcn_mfma_f32_16x16x32_bf16(a[kt], bv, acc[nt], 0, 0, 0);
        }
    }
    float* Yg = Y + (g * NPG + mrow) * OUTF + ncol;
#pragma unroll
    for (int nt = 0; nt < 4; ++nt) {
        float bv = bias[h * OUTF + ncol + nt * 16 + l16];
#pragma unroll
        for (int r = 0; r < 4; ++r)
            Yg[(quad * 4 + r) * OUTF + nt * 16 + l16] = acc[nt][r] + bv;
    }
}

extern "C" void kernel_launch(void* const* d_in, const int* in_sizes, int n_in,
                              void* d_out, int out_size, void* d_ws, size_t ws_size,
                              hipStream_t stream) {
    // setup_inputs order: inputs, n_node, head, kernel, bias
    const float* X    = (const float*)d_in[0];
    const int*   head = (const int*)d_in[2];
    const float* W    = (const float*)d_in[3];
    const float* bias = (const float*)d_in[4];
    float* Y = (float*)d_out;

    const size_t wt_bytes = (size_t)NH * OUTF * INF * sizeof(unsigned short);  // 512 KiB
    if (d_ws != nullptr && ws_size >= wt_bytes) {
        unsigned short* Wt = (unsigned short*)d_ws;
        wconv_kernel<<<NH * 8, 256, 0, stream>>>(W, Wt);           // ~1 MiB, one-shot
        mhl_gemm_kernel<<<NG, 512, 0, stream>>>(X, head, Wt, bias, Y);
    } else {
        mhl_fused_kernel<<<NG, 512, 0, stream>>>(X, head, W, bias, Y);
    }
}

// Round 2
// 69.679 us; speedup vs baseline: 1.0711x; 1.0711x over previous
//
#include <hip/hip_runtime.h>

// Problem constants (fixed by setup_inputs)
#define NG   256   // graphs
#define NPG  64    // nodes per graph
#define INF  128   // in features (K)
#define OUTF 128   // out features (N)
#define NH   16    // heads

// LDS row stride for Wl[n][k] in bf16 units.
// 136 bf16 = 272 B = 68 dwords: rows stay 16B-aligned (ds_read_b128 ok) and
// the b128 B-fragment read pattern (start bank 4*(n+quad) % 32) spreads the
// wave's 64 lanes x 4 dwords uniformly at 8 dwords/bank = conflict-free floor.
#define LDSK 136

typedef __attribute__((ext_vector_type(8))) short bf16x8;  // 8 bf16 = 4 VGPRs
typedef __attribute__((ext_vector_type(4))) float f32x4;   // MFMA accumulator

__device__ __forceinline__ unsigned short f2bf(float f) {
    union { float f; unsigned int i; } c; c.f = f;
    unsigned int r = c.i + 0x7fffu + ((c.i >> 16) & 1u);  // round-to-nearest-even
    return (unsigned short)(r >> 16);
}

// One block per graph (grid 256 = 1 block/CU), 512 threads = 8 waves.
//
// Order of operations is the optimization:
//   1. X float4 loads issued FIRST (independent of head; cold-HBM latency
//      hides under the whole W staging phase + barrier).
//   2. W[h] staged to LDS transposed (Wl[n][k] bf16) with VECTORIZED writes:
//      each thread reads 8 k-strided float2 (each instr = one full 512 B
//      W row across the wave, fully coalesced), converts, and writes two
//      ds_write_b128 (vs 32 bank-conflicted ds_write_b16 previously).
//   3. Barrier, then MFMA on the harness-verified read path (unchanged).
__global__ __launch_bounds__(512) void mhl_fused_kernel(
    const float* __restrict__ X,     // [NG*NPG][INF] fp32
    const int*   __restrict__ head,  // [NG]
    const float* __restrict__ W,     // [NH][INF][OUTF] fp32
    const float* __restrict__ bias,  // [NH][OUTF] fp32
    float*       __restrict__ Y)     // [NG*NPG][OUTF] fp32
{
    __shared__ __align__(16) unsigned short Wl[OUTF * LDSK];  // 34816 B

    int g = (int)blockIdx.x;
    int t = (int)threadIdx.x;
    int wave = t >> 6, lane = t & 63;
    int quad = lane >> 4, l16 = lane & 15;
    int mrow = (wave & 3) * 16;    // row tile within graph
    int ncol = (wave >> 2) * 64;   // column half

    // ---- 1) Issue X loads up front (in flight during staging + barrier) ----
    const float* Xg = X + (g * NPG + mrow + l16) * INF + quad * 8;
    float4 xv[8];
#pragma unroll
    for (int kt = 0; kt < 4; ++kt) {
        xv[2 * kt]     = *(const float4*)(Xg + kt * 32);
        xv[2 * kt + 1] = *(const float4*)(Xg + kt * 32 + 4);
    }

    int h = head[g];  // uniform -> s_load

    // ---- 2) Stage W[h] -> Wl[n][k] bf16, vectorized ----
    // idx in [0,1024): column pair n0=2*(idx&63), k-chunk k0=8*(idx>>6).
    // Loads: j=0..7, W[k0+j][n0..n0+1] -- each instruction covers one full
    // 512 B k-row across the wave's 64 lanes (fully coalesced).
    // Writes: two ds_write_b128, k-contiguous in the n-row of Wl.
    {
        const float* Wh = W + h * (INF * OUTF);
#pragma unroll
        for (int c = 0; c < 2; ++c) {
            int idx = c * 512 + t;
            int n0 = (idx & 63) * 2;
            int k0 = (idx >> 6) * 8;
            float2 v[8];
#pragma unroll
            for (int j = 0; j < 8; ++j)
                v[j] = *(const float2*)(Wh + (k0 + j) * OUTF + n0);
            bf16x8 a0, a1;
#pragma unroll
            for (int j = 0; j < 8; ++j) {
                a0[j] = (short)f2bf(v[j].x);
                a1[j] = (short)f2bf(v[j].y);
            }
            *(bf16x8*)(&Wl[(n0 + 0) * LDSK + k0]) = a0;
            *(bf16x8*)(&Wl[(n0 + 1) * LDSK + k0]) = a1;
        }
    }

    // bias loads issued before the barrier too (independent of LDS)
    float bv[4];
#pragma unroll
    for (int nt = 0; nt < 4; ++nt)
        bv[nt] = bias[h * OUTF + ncol + nt * 16 + l16];

    __syncthreads();

    // ---- 3) A fragments: convert the prefetched X rows ----
    bf16x8 a[4];
#pragma unroll
    for (int kt = 0; kt < 4; ++kt) {
        float vv[8] __attribute__((aligned(16)));
        *(float4*)(&vv[0]) = xv[2 * kt];
        *(float4*)(&vv[4]) = xv[2 * kt + 1];
#pragma unroll
        for (int j = 0; j < 8; ++j) a[kt][j] = (short)f2bf(vv[j]);
    }

    f32x4 acc[4];
#pragma unroll
    for (int nt = 0; nt < 4; ++nt) acc[nt] = (f32x4){0.f, 0.f, 0.f, 0.f};

    // B fragments: harness-verified read path (unchanged from round 0).
    // b[j] = B[k=quad*8+kt*32+j][n], k-contiguous in Wl.
#pragma unroll
    for (int nt = 0; nt < 4; ++nt) {
        const unsigned short* Wn = &Wl[(ncol + nt * 16 + l16) * LDSK + quad * 8];
#pragma unroll
        for (int kt = 0; kt < 4; ++kt) {
            bf16x8 b = *(const bf16x8*)(Wn + kt * 32);
            acc[nt] = __builtin_amdgcn_mfma_f32_16x16x32_bf16(a[kt], b, acc[nt], 0, 0, 0);
        }
    }

    // ---- Epilogue: C/D layout col=lane&15, row=quad*4+reg (m89-verified) ----
    float* Yg = Y + (g * NPG + mrow) * OUTF + ncol;
#pragma unroll
    for (int nt = 0; nt < 4; ++nt) {
#pragma unroll
        for (int r = 0; r < 4; ++r)
            __builtin_nontemporal_store(acc[nt][r] + bv[nt],
                &Yg[(quad * 4 + r) * OUTF + nt * 16 + l16]);
    }
}

extern "C" void kernel_launch(void* const* d_in, const int* in_sizes, int n_in,
                              void* d_out, int out_size, void* d_ws, size_t ws_size,
                              hipStream_t stream) {
    // setup_inputs order: inputs, n_node, head, kernel, bias
    const float* X    = (const float*)d_in[0];
    const int*   head = (const int*)d_in[2];
    const float* W    = (const float*)d_in[3];
    const float* bias = (const float*)d_in[4];
    float* Y = (float*)d_out;

    mhl_fused_kernel<<<NG, 512, 0, stream>>>(X, head, W, bias, Y);
}